// Round 3
// baseline (3345.052 us; speedup 1.0000x reference)
//
#include <hip/hip_runtime.h>
#include <stdint.h>

// W8A16 GEMM: out[m,n] = s[n] * sum_k a[m,k] * q_int8[k,n] + bias[n]
// M=8192 (B*S), N=16384, K=4096.
// Harness dtype model (derived R2): fp16 reference arrays arrive as f32;
// int8 qweight arrives as int32; OUTPUT is f32.
// A f32 -> bf16 (rounding, ~0.03 abs err after scale); Q int -> bf16 exact.
// Inner loop = pure bf16 MFMA GEMM; scale+bias in f32 epilogue.

typedef __bf16 bf16x8 __attribute__((ext_vector_type(8)));
typedef float  f32x4  __attribute__((ext_vector_type(4)));

#define M_TOT 8192
#define N_TOT 16384
#define K_TOT 4096
#define BM 128
#define BN 128
#define BK 32
#define BSTRIDE 40  // padded k-stride for b_lds: 80B -> B reads 2-way (free)

__global__ void __launch_bounds__(256)
w8a16_gemm_kernel(const float* __restrict__ A,   // [M,K] f32 (fp16 values)
                  const int*   __restrict__ Q,   // [K,N] int32 (int8 values)
                  const float* __restrict__ S,   // [N] scales f32
                  const float* __restrict__ Bias,// [N] bias f32
                  float*       __restrict__ O)   // [M,N] f32
{
  __shared__ __bf16 a_lds[BM * BK];        // [128][32], col-chunk swizzled
  __shared__ __bf16 b_lds[BN * BSTRIDE];   // [128][40] padded, [n][k]

  const int tid  = threadIdx.x;
  const int lane = tid & 63;
  const int wv   = tid >> 6;

  // Bijective XCD swizzle: 8192 blocks = 8 XCDs x 1024. by fastest ->
  // one B column-panel (8MB int32) streams while A M-tiles reuse L2.
  const int bid = blockIdx.x;
  const int swz = (bid & 7) * 1024 + (bid >> 3);
  const int bx  = swz >> 6;          // [0,128) N-tile
  const int by  = swz & 63;          // [0,64)  M-tile
  const int m0  = by * BM;
  const int n0  = bx * BN;

  // ---- A staging (register-staged f32 -> bf16, 2 chunks of 8 per thread) ----
  // idx in {tid, 256+tid}: m = idx>>2, kc = idx&3 (8-elem chunk).
  // LDS chunk column kc' = kc ^ (m&3) ^ ((m>>2)&1)  -> read side 2-way (free).
  const int mA0 = tid >> 2;
  const int mA1 = (256 + tid) >> 2;
  const int kcA = tid & 3;                    // same for both (256 % 4 == 0)
  const int kp0 = kcA ^ (mA0 & 3) ^ ((mA0 >> 2) & 1);
  const int kp1 = kcA ^ (mA1 & 3) ^ ((mA1 >> 2) & 1);
  const float* pA0 = A + (size_t)(m0 + mA0) * K_TOT + kcA * 8;
  const float* pA1 = A + (size_t)(m0 + mA1) * K_TOT + kcA * 8;
  __bf16* dA0 = a_lds + mA0 * BK + kp0 * 8;
  __bf16* dA1 = a_lds + mA1 * BK + kp1 * 8;

  // ---- B staging: one column per thread, 16 k-rows, coalesced dword loads ----
  const int nB = tid & 127;
  const int kg = (tid >> 7) * 16;
  const int* pQ = Q + (size_t)kg * N_TOT + n0 + nB;
  __bf16* dB = b_lds + nB * BSTRIDE + kg;

  // ---- compute-phase constants ----
  const int wr   = (wv >> 1) * 64;   // wave row offset
  const int wc   = (wv & 1) * 64;    // wave col offset
  const int r15  = lane & 15;
  const int kgrp = lane >> 4;        // which 8-elem k-chunk this lane needs
  const int selA = kgrp ^ (r15 & 3) ^ ((r15 >> 2) & 1);
  const __bf16* aRd = a_lds + (wr + r15) * BK + selA * 8;
  const __bf16* bRd = b_lds + (wc + r15) * BSTRIDE + kgrp * 8;

  f32x4 acc[4][4];
  #pragma unroll
  for (int i = 0; i < 4; ++i)
    #pragma unroll
    for (int j = 0; j < 4; ++j)
      acc[i][j] = {0.f, 0.f, 0.f, 0.f};

  for (int kt = 0; kt < K_TOT / BK; ++kt) {
    // A: global f32 -> regs -> cvt bf16 -> LDS
    f32x4 a0lo = *(const f32x4*)(pA0);
    f32x4 a0hi = *(const f32x4*)(pA0 + 4);
    f32x4 a1lo = *(const f32x4*)(pA1);
    f32x4 a1hi = *(const f32x4*)(pA1 + 4);
    pA0 += BK; pA1 += BK;
    bf16x8 a0, a1;
    #pragma unroll
    for (int i = 0; i < 4; ++i) {
      a0[i]     = (__bf16)a0lo[i];
      a0[i + 4] = (__bf16)a0hi[i];
      a1[i]     = (__bf16)a1lo[i];
      a1[i + 4] = (__bf16)a1hi[i];
    }

    // B: 16 int32 down column nB, convert to bf16 (exact)
    int qv[16];
    #pragma unroll
    for (int i = 0; i < 16; ++i) qv[i] = pQ[(size_t)i * N_TOT];
    pQ += (size_t)BK * N_TOT;
    bf16x8 v0, v1;
    #pragma unroll
    for (int i = 0; i < 8; ++i) v0[i] = (__bf16)(float)qv[i];
    #pragma unroll
    for (int i = 0; i < 8; ++i) v1[i] = (__bf16)(float)qv[i + 8];

    *(bf16x8*)dA0      = a0;
    *(bf16x8*)dA1      = a1;
    *(bf16x8*)(dB)     = v0;
    *(bf16x8*)(dB + 8) = v1;

    __syncthreads();

    bf16x8 af[4], bfr[4];
    #pragma unroll
    for (int mi = 0; mi < 4; ++mi)
      af[mi] = *(const bf16x8*)(aRd + mi * 16 * BK);
    #pragma unroll
    for (int ni = 0; ni < 4; ++ni)
      bfr[ni] = *(const bf16x8*)(bRd + ni * 16 * BSTRIDE);

    #pragma unroll
    for (int mi = 0; mi < 4; ++mi)
      #pragma unroll
      for (int ni = 0; ni < 4; ++ni)
        acc[mi][ni] = __builtin_amdgcn_mfma_f32_16x16x32_bf16(
            af[mi], bfr[ni], acc[mi][ni], 0, 0, 0);

    __syncthreads();
  }

  // ---- epilogue: per-column scale + bias in f32, store f32 ----
  // C/D layout: col = lane&15, row = (lane>>4)*4 + reg_idx   [m89-verified]
  const int colb = n0 + wc + r15;
  const int rowb = m0 + wr + kgrp * 4;
  #pragma unroll
  for (int ni = 0; ni < 4; ++ni) {
    const int col = colb + ni * 16;
    const float sc = S[col];
    const float bb = Bias[col];
    #pragma unroll
    for (int mi = 0; mi < 4; ++mi) {
      const int row = rowb + mi * 16;
      f32x4 a = acc[mi][ni];
      #pragma unroll
      for (int j = 0; j < 4; ++j)
        O[(size_t)(row + j) * N_TOT + col] = a[j] * sc + bb;
    }
  }
}

extern "C" void kernel_launch(void* const* d_in, const int* in_sizes, int n_in,
                              void* d_out, int out_size, void* d_ws, size_t ws_size,
                              hipStream_t stream) {
  const float* A    = (const float*)d_in[0];
  const int*   Q    = (const int*)d_in[1];
  const float* S    = (const float*)d_in[2];
  const float* Bias = (const float*)d_in[3];
  float*       O    = (float*)d_out;

  w8a16_gemm_kernel<<<dim3(8192), dim3(256), 0, stream>>>(A, Q, S, Bias, O);
}

// Round 4
// 2011.404 us; speedup vs baseline: 1.6630x; 1.6630x over previous
//
#include <hip/hip_runtime.h>
#include <stdint.h>

// W8A16 GEMM: out[m,n] = s[n] * sum_k a[m,k] * q_int8[k,n] + bias[n]
// M=8192, N=16384, K=4096. Harness dtypes: A,S,Bias f32; Q int32; OUT f32.
//
// Round 4: pre-pass dequant into d_ws (A->bf16, Q->bf16 transposed [N][K]),
// then pure bf16 MFMA GEMM in m97 structure: global_load_lds width-16 for
// BOTH operands, no in-loop cvt, no ds_writes. Fallback to fused kernel if
// ws_size is too small.

typedef __bf16 bf16x8 __attribute__((ext_vector_type(8)));
typedef float  f32x4  __attribute__((ext_vector_type(4)));

#define M_TOT 8192
#define N_TOT 16384
#define K_TOT 4096
#define BM 128
#define BN 128
#define BK 32

__device__ __forceinline__ void gload_lds16(const void* g, void* l) {
  __builtin_amdgcn_global_load_lds(
      (const __attribute__((address_space(1))) unsigned int*)g,
      (__attribute__((address_space(3))) unsigned int*)l,
      16, 0, 0);
}

// chunk swizzle: s(row) = (row&3) ^ ((row>>2)&1) -> read-side 2-way (free)
__device__ __forceinline__ int swz_s(int row) {
  return (row & 3) ^ ((row >> 2) & 1);
}

// ---------------- pre-pass 1: A f32 -> bf16 ----------------
__global__ void __launch_bounds__(256)
cvt_a_kernel(const float* __restrict__ A, __bf16* __restrict__ Abf) {
  const size_t i = ((size_t)blockIdx.x * 256 + threadIdx.x) * 8;
  f32x4 lo = *(const f32x4*)(A + i);
  f32x4 hi = *(const f32x4*)(A + i + 4);
  bf16x8 v;
  #pragma unroll
  for (int j = 0; j < 4; ++j) {
    v[j]     = (__bf16)lo[j];
    v[j + 4] = (__bf16)hi[j];
  }
  *(bf16x8*)(Abf + i) = v;
}

// ---------------- pre-pass 2: Q [K][N] int32 -> Bt [N][K] bf16 ----------------
// 64x64 tile per block; reads coalesced (lane = n), each thread owns 16
// consecutive k for one n -> writes two 16B chunks of the transposed row.
__global__ void __launch_bounds__(256)
transpose_q_kernel(const int* __restrict__ Q, __bf16* __restrict__ Bt) {
  const int bk = blockIdx.x & 63;        // 64 k-tiles
  const int bn = blockIdx.x >> 6;        // 256 n-tiles
  const int k0 = bk * 64, n0 = bn * 64;
  const int tx = threadIdx.x & 63;       // n within tile
  const int ty = threadIdx.x >> 6;       // k-chunk of 16
  const int kb = k0 + ty * 16;
  const int n  = n0 + tx;
  int q[16];
  #pragma unroll
  for (int i = 0; i < 16; ++i)
    q[i] = Q[(size_t)(kb + i) * N_TOT + n];
  bf16x8 v0, v1;
  #pragma unroll
  for (int i = 0; i < 8; ++i) {
    v0[i] = (__bf16)(float)q[i];
    v1[i] = (__bf16)(float)q[i + 8];
  }
  *(bf16x8*)(Bt + (size_t)n * K_TOT + kb)     = v0;
  *(bf16x8*)(Bt + (size_t)n * K_TOT + kb + 8) = v1;
}

// ---------------- main GEMM (m97 structure, both operands bf16 [row][K]) ----
__global__ void __launch_bounds__(256)
w8a16_gemm_ws(const __bf16* __restrict__ A,   // [M,K] bf16
              const __bf16* __restrict__ Bt,  // [N,K] bf16
              const float*  __restrict__ S,
              const float*  __restrict__ Bias,
              float*        __restrict__ O)
{
  __shared__ __bf16 a_lds[BM * BK];  // [128][32] linear dest (gload_lds)
  __shared__ __bf16 b_lds[BN * BK];  // [128][32]

  const int tid  = threadIdx.x;
  const int lane = tid & 63;
  const int wv   = tid >> 6;

  // Bijective XCD swizzle: 8192 blocks = 8 XCDs x 1024, M-tile fastest.
  const int bid = blockIdx.x;
  const int swz = (bid & 7) * 1024 + (bid >> 3);
  const int bx  = swz >> 6;          // [0,128) N-tile
  const int by  = swz & 63;          // [0,64)  M-tile
  const int m0  = by * BM;
  const int n0  = bx * BN;

  // staging: chunk idx = i*256+tid (i=0,1); row = idx>>2, c = idx&3.
  // LDS[row][c] <- data(row, c ^ s(row))  [inverse-swizzled source]
  const int r0 = tid >> 2, r1 = (256 + tid) >> 2;
  const int c0 = tid & 3;
  const int cs0 = c0 ^ swz_s(r0);
  const int cs1 = c0 ^ swz_s(r1);
  const __bf16* pa0 = A  + (size_t)(m0 + r0) * K_TOT + cs0 * 8;
  const __bf16* pa1 = A  + (size_t)(m0 + r1) * K_TOT + cs1 * 8;
  const __bf16* pb0 = Bt + (size_t)(n0 + r0) * K_TOT + cs0 * 8;
  const __bf16* pb1 = Bt + (size_t)(n0 + r1) * K_TOT + cs1 * 8;
  __bf16* da0 = a_lds + (size_t)tid * 8;
  __bf16* da1 = a_lds + (size_t)(256 + tid) * 8;
  __bf16* db0 = b_lds + (size_t)tid * 8;
  __bf16* db1 = b_lds + (size_t)(256 + tid) * 8;

  // compute-phase constants
  const int wr   = (wv >> 1) * 64;
  const int wc   = (wv & 1) * 64;
  const int r15  = lane & 15;
  const int kgrp = lane >> 4;
  const int sel  = kgrp ^ swz_s(r15);   // row&3,(row>>2)&1 depend only on r15
  const __bf16* aRd = a_lds + (wr + r15) * BK + sel * 8;
  const __bf16* bRd = b_lds + (wc + r15) * BK + sel * 8;

  f32x4 acc[4][4];
  #pragma unroll
  for (int i = 0; i < 4; ++i)
    #pragma unroll
    for (int j = 0; j < 4; ++j)
      acc[i][j] = {0.f, 0.f, 0.f, 0.f};

  for (int kt = 0; kt < K_TOT / BK; ++kt) {
    gload_lds16(pa0, da0);
    gload_lds16(pa1, da1);
    gload_lds16(pb0, db0);
    gload_lds16(pb1, db1);
    pa0 += BK; pa1 += BK; pb0 += BK; pb1 += BK;

    __syncthreads();

    bf16x8 af[4], bfr[4];
    #pragma unroll
    for (int mi = 0; mi < 4; ++mi)
      af[mi] = *(const bf16x8*)(aRd + mi * 16 * BK);
    #pragma unroll
    for (int ni = 0; ni < 4; ++ni)
      bfr[ni] = *(const bf16x8*)(bRd + ni * 16 * BK);

    #pragma unroll
    for (int mi = 0; mi < 4; ++mi)
      #pragma unroll
      for (int ni = 0; ni < 4; ++ni)
        acc[mi][ni] = __builtin_amdgcn_mfma_f32_16x16x32_bf16(
            af[mi], bfr[ni], acc[mi][ni], 0, 0, 0);

    __syncthreads();
  }

  // epilogue: scale+bias in f32.  C/D: col=lane&15, row=(lane>>4)*4+reg
  const int colb = n0 + wc + r15;
  const int rowb = m0 + wr + kgrp * 4;
  #pragma unroll
  for (int ni = 0; ni < 4; ++ni) {
    const int col = colb + ni * 16;
    const float sc = S[col];
    const float bb = Bias[col];
    #pragma unroll
    for (int mi = 0; mi < 4; ++mi) {
      const int row = rowb + mi * 16;
      f32x4 a = acc[mi][ni];
      #pragma unroll
      for (int j = 0; j < 4; ++j)
        O[(size_t)(row + j) * N_TOT + col] = a[j] * sc + bb;
    }
  }
}

// ---------------- fallback: round-3 fused kernel (ws too small) ----------------
#define BSTRIDE 40
__global__ void __launch_bounds__(256)
w8a16_gemm_fused(const float* __restrict__ A, const int* __restrict__ Q,
                 const float* __restrict__ S, const float* __restrict__ Bias,
                 float* __restrict__ O)
{
  __shared__ __bf16 a_lds[BM * BK];
  __shared__ __bf16 b_lds[BN * BSTRIDE];
  const int tid = threadIdx.x, lane = tid & 63, wv = tid >> 6;
  const int bid = blockIdx.x;
  const int swz = (bid & 7) * 1024 + (bid >> 3);
  const int bx = swz >> 6, by = swz & 63;
  const int m0 = by * BM, n0 = bx * BN;
  const int mA0 = tid >> 2, mA1 = (256 + tid) >> 2;
  const int kcA = tid & 3;
  const int kp0 = kcA ^ swz_s(mA0), kp1 = kcA ^ swz_s(mA1);
  const float* pA0 = A + (size_t)(m0 + mA0) * K_TOT + kcA * 8;
  const float* pA1 = A + (size_t)(m0 + mA1) * K_TOT + kcA * 8;
  __bf16* dA0 = a_lds + mA0 * BK + kp0 * 8;
  __bf16* dA1 = a_lds + mA1 * BK + kp1 * 8;
  const int nB = tid & 127, kg = (tid >> 7) * 16;
  const int* pQ = Q + (size_t)kg * N_TOT + n0 + nB;
  __bf16* dB = b_lds + nB * BSTRIDE + kg;
  const int wr = (wv >> 1) * 64, wc = (wv & 1) * 64;
  const int r15 = lane & 15, kgrp = lane >> 4;
  const int selA = kgrp ^ swz_s(r15);
  const __bf16* aRd = a_lds + (wr + r15) * BK + selA * 8;
  const __bf16* bRd = b_lds + (wc + r15) * BSTRIDE + kgrp * 8;
  f32x4 acc[4][4];
  #pragma unroll
  for (int i = 0; i < 4; ++i)
    #pragma unroll
    for (int j = 0; j < 4; ++j) acc[i][j] = {0.f, 0.f, 0.f, 0.f};
  for (int kt = 0; kt < K_TOT / BK; ++kt) {
    f32x4 a0lo = *(const f32x4*)(pA0), a0hi = *(const f32x4*)(pA0 + 4);
    f32x4 a1lo = *(const f32x4*)(pA1), a1hi = *(const f32x4*)(pA1 + 4);
    pA0 += BK; pA1 += BK;
    bf16x8 a0, a1;
    #pragma unroll
    for (int i = 0; i < 4; ++i) {
      a0[i] = (__bf16)a0lo[i]; a0[i + 4] = (__bf16)a0hi[i];
      a1[i] = (__bf16)a1lo[i]; a1[i + 4] = (__bf16)a1hi[i];
    }
    int qv[16];
    #pragma unroll
    for (int i = 0; i < 16; ++i) qv[i] = pQ[(size_t)i * N_TOT];
    pQ += (size_t)BK * N_TOT;
    bf16x8 v0, v1;
    #pragma unroll
    for (int i = 0; i < 8; ++i) { v0[i] = (__bf16)(float)qv[i]; v1[i] = (__bf16)(float)qv[i + 8]; }
    *(bf16x8*)dA0 = a0; *(bf16x8*)dA1 = a1;
    *(bf16x8*)(dB) = v0; *(bf16x8*)(dB + 8) = v1;
    __syncthreads();
    bf16x8 af[4], bfr[4];
    #pragma unroll
    for (int mi = 0; mi < 4; ++mi) af[mi] = *(const bf16x8*)(aRd + mi * 16 * BK);
    #pragma unroll
    for (int ni = 0; ni < 4; ++ni) bfr[ni] = *(const bf16x8*)(bRd + ni * 16 * BSTRIDE);
    #pragma unroll
    for (int mi = 0; mi < 4; ++mi)
      #pragma unroll
      for (int ni = 0; ni < 4; ++ni)
        acc[mi][ni] = __builtin_amdgcn_mfma_f32_16x16x32_bf16(af[mi], bfr[ni], acc[mi][ni], 0, 0, 0);
    __syncthreads();
  }
  const int colb = n0 + wc + r15, rowb = m0 + wr + kgrp * 4;
  #pragma unroll
  for (int ni = 0; ni < 4; ++ni) {
    const int col = colb + ni * 16;
    const float sc = S[col], bb = Bias[col];
    #pragma unroll
    for (int mi = 0; mi < 4; ++mi) {
      const int row = rowb + mi * 16;
      f32x4 a = acc[mi][ni];
      #pragma unroll
      for (int j = 0; j < 4; ++j)
        O[(size_t)(row + j) * N_TOT + col] = a[j] * sc + bb;
    }
  }
}

extern "C" void kernel_launch(void* const* d_in, const int* in_sizes, int n_in,
                              void* d_out, int out_size, void* d_ws, size_t ws_size,
                              hipStream_t stream) {
  const float* A    = (const float*)d_in[0];
  const int*   Q    = (const int*)d_in[1];
  const float* S    = (const float*)d_in[2];
  const float* Bias = (const float*)d_in[3];
  float*       O    = (float*)d_out;

  const size_t A_BYTES = (size_t)M_TOT * K_TOT * 2;   // 64 MiB
  const size_t B_BYTES = (size_t)N_TOT * K_TOT * 2;   // 128 MiB

  if (ws_size >= A_BYTES + B_BYTES) {
    __bf16* Abf = (__bf16*)d_ws;
    __bf16* Bt  = (__bf16*)((char*)d_ws + A_BYTES);
    // A: 8192*4096/8 elems per thread-8 = 16384 blocks * 256
    cvt_a_kernel<<<dim3(16384), dim3(256), 0, stream>>>(A, Abf);
    // Q: (4096/64)*(16384/64) = 16384 tiles
    transpose_q_kernel<<<dim3(16384), dim3(256), 0, stream>>>(Q, Bt);
    // GEMM: 64*128 = 8192 blocks
    w8a16_gemm_ws<<<dim3(8192), dim3(256), 0, stream>>>(Abf, Bt, S, Bias, O);
  } else {
    w8a16_gemm_fused<<<dim3(8192), dim3(256), 0, stream>>>(A, Q, S, Bias, O);
  }
}

// Round 5
// 1559.858 us; speedup vs baseline: 2.1445x; 1.2895x over previous
//
#include <hip/hip_runtime.h>
#include <stdint.h>

// W8A16 GEMM: out[m,n] = s[n] * sum_k a[m,k] * q_int8[k,n] + bias[n]
// M=8192, N=16384, K=4096. Harness dtypes: A,S,Bias f32; Q int32; OUT f32.
//
// Round 5: 2-phase double-buffered pipeline (T3-min): stage(t+1) overlaps
// compute(t); raw s_barrier + counted vmcnt(4) (no __syncthreads vmcnt(0)
// drain). Supertile (16bx x 16by) block mapping per XCD chunk for L2/L3.

typedef __bf16 bf16x8 __attribute__((ext_vector_type(8)));
typedef float  f32x4  __attribute__((ext_vector_type(4)));

#define M_TOT 8192
#define N_TOT 16384
#define K_TOT 4096
#define BM 128
#define BN 128
#define BK 32
#define NT (K_TOT / BK)   // 128 K-tiles

__device__ __forceinline__ void gload_lds16(const void* g, void* l) {
  __builtin_amdgcn_global_load_lds(
      (const __attribute__((address_space(1))) unsigned int*)g,
      (__attribute__((address_space(3))) unsigned int*)l,
      16, 0, 0);
}

// chunk swizzle: s(row) = (row&3) ^ ((row>>2)&1)
__device__ __forceinline__ int swz_s(int row) {
  return (row & 3) ^ ((row >> 2) & 1);
}

// ---------------- pre-pass 1: A f32 -> bf16 ----------------
__global__ void __launch_bounds__(256)
cvt_a_kernel(const float* __restrict__ A, __bf16* __restrict__ Abf) {
  const size_t i = ((size_t)blockIdx.x * 256 + threadIdx.x) * 8;
  f32x4 lo = *(const f32x4*)(A + i);
  f32x4 hi = *(const f32x4*)(A + i + 4);
  bf16x8 v;
  #pragma unroll
  for (int j = 0; j < 4; ++j) {
    v[j]     = (__bf16)lo[j];
    v[j + 4] = (__bf16)hi[j];
  }
  *(bf16x8*)(Abf + i) = v;
}

// ---------------- pre-pass 2: Q [K][N] int32 -> Bt [N][K] bf16 ----------------
__global__ void __launch_bounds__(256)
transpose_q_kernel(const int* __restrict__ Q, __bf16* __restrict__ Bt) {
  const int bk = blockIdx.x & 63;        // 64 k-tiles
  const int bn = blockIdx.x >> 6;        // 256 n-tiles
  const int k0 = bk * 64, n0 = bn * 64;
  const int tx = threadIdx.x & 63;       // n within tile
  const int ty = threadIdx.x >> 6;       // k-chunk of 16
  const int kb = k0 + ty * 16;
  const int n  = n0 + tx;
  int q[16];
  #pragma unroll
  for (int i = 0; i < 16; ++i)
    q[i] = Q[(size_t)(kb + i) * N_TOT + n];
  bf16x8 v0, v1;
  #pragma unroll
  for (int i = 0; i < 8; ++i) {
    v0[i] = (__bf16)(float)q[i];
    v1[i] = (__bf16)(float)q[i + 8];
  }
  *(bf16x8*)(Bt + (size_t)n * K_TOT + kb)     = v0;
  *(bf16x8*)(Bt + (size_t)n * K_TOT + kb + 8) = v1;
}

// ---------------- main GEMM: 2-phase double-buffered m97 structure ----------
__global__ void __launch_bounds__(256, 4)
w8a16_gemm_ws(const __bf16* __restrict__ A,   // [M,K] bf16
              const __bf16* __restrict__ Bt,  // [N,K] bf16
              const float*  __restrict__ S,
              const float*  __restrict__ Bias,
              float*        __restrict__ O)
{
  __shared__ __bf16 a_lds[2][BM * BK];  // double-buffered, linear dest
  __shared__ __bf16 b_lds[2][BN * BK];

  const int tid  = threadIdx.x;
  const int lane = tid & 63;
  const int wv   = tid >> 6;

  // XCD chunk + 16x16 supertile mapping (bijective):
  // xcd = bid&7; c = bid>>3 in [0,1024); s = c>>8 (by-window of 16);
  // i = c&255: bx_loc = i>>4, by_off = i&15 (by fastest).
  const int bid    = blockIdx.x;
  const int xcd    = bid & 7;
  const int c      = bid >> 3;
  const int sphase = c >> 8;
  const int i256   = c & 255;
  const int bx     = xcd * 16 + (i256 >> 4);   // [0,128) N-tile
  const int by     = sphase * 16 + (i256 & 15);// [0,64)  M-tile
  const int m0     = by * BM;
  const int n0     = bx * BN;

  // staging: chunk idx = i*256+tid (i=0,1); row = idx>>2, c = idx&3.
  // LDS[row][c] <- data(row, c ^ s(row))  [inverse-swizzled source]
  const int r0 = tid >> 2, r1 = (256 + tid) >> 2;
  const int c0 = tid & 3;
  const int cs0 = c0 ^ swz_s(r0);
  const int cs1 = c0 ^ swz_s(r1);
  const __bf16* pa0 = A  + (size_t)(m0 + r0) * K_TOT + cs0 * 8;
  const __bf16* pa1 = A  + (size_t)(m0 + r1) * K_TOT + cs1 * 8;
  const __bf16* pb0 = Bt + (size_t)(n0 + r0) * K_TOT + cs0 * 8;
  const __bf16* pb1 = Bt + (size_t)(n0 + r1) * K_TOT + cs1 * 8;
  const int d0 = tid * 8;
  const int d1 = (256 + tid) * 8;

  // compute-phase constants
  const int wr   = (wv >> 1) * 64;
  const int wc   = (wv & 1) * 64;
  const int r15  = lane & 15;
  const int kgrp = lane >> 4;
  const int sel  = kgrp ^ swz_s(r15);
  const int aOff = (wr + r15) * BK + sel * 8;
  const int bOff = (wc + r15) * BK + sel * 8;

  f32x4 acc[4][4];
  #pragma unroll
  for (int i = 0; i < 4; ++i)
    #pragma unroll
    for (int j = 0; j < 4; ++j)
      acc[i][j] = {0.f, 0.f, 0.f, 0.f};

  // prologue: stage tile 0 into buf 0
  gload_lds16(pa0, &a_lds[0][d0]);
  gload_lds16(pa1, &a_lds[0][d1]);
  gload_lds16(pb0, &b_lds[0][d0]);
  gload_lds16(pb1, &b_lds[0][d1]);
  pa0 += BK; pa1 += BK; pb0 += BK; pb1 += BK;

  for (int kt = 0; kt < NT - 1; ++kt) {
    const int cb = kt & 1;
    const int nb = cb ^ 1;

    // stage tile kt+1 into buf nb (stays in flight across the barrier)
    gload_lds16(pa0, &a_lds[nb][d0]);
    gload_lds16(pa1, &a_lds[nb][d1]);
    gload_lds16(pb0, &b_lds[nb][d0]);
    gload_lds16(pb1, &b_lds[nb][d1]);
    pa0 += BK; pa1 += BK; pb0 += BK; pb1 += BK;

    // wait only for tile kt's 4 loads (4 newest stay outstanding)
    asm volatile("s_waitcnt vmcnt(4)" ::: "memory");
    __builtin_amdgcn_s_barrier();
    __builtin_amdgcn_sched_barrier(0);

    bf16x8 af[4], bfr[4];
    #pragma unroll
    for (int mi = 0; mi < 4; ++mi)
      af[mi] = *(const bf16x8*)(&a_lds[cb][aOff + mi * 16 * BK]);
    #pragma unroll
    for (int ni = 0; ni < 4; ++ni)
      bfr[ni] = *(const bf16x8*)(&b_lds[cb][bOff + ni * 16 * BK]);

    #pragma unroll
    for (int mi = 0; mi < 4; ++mi)
      #pragma unroll
      for (int ni = 0; ni < 4; ++ni)
        acc[mi][ni] = __builtin_amdgcn_mfma_f32_16x16x32_bf16(
            af[mi], bfr[ni], acc[mi][ni], 0, 0, 0);

    // all waves consumed buf cb -> next iter may overwrite it
    __builtin_amdgcn_s_barrier();
  }

  // tail: compute last tile (buf (NT-1)&1)
  {
    const int cb = (NT - 1) & 1;
    asm volatile("s_waitcnt vmcnt(0)" ::: "memory");
    __builtin_amdgcn_s_barrier();
    __builtin_amdgcn_sched_barrier(0);

    bf16x8 af[4], bfr[4];
    #pragma unroll
    for (int mi = 0; mi < 4; ++mi)
      af[mi] = *(const bf16x8*)(&a_lds[cb][aOff + mi * 16 * BK]);
    #pragma unroll
    for (int ni = 0; ni < 4; ++ni)
      bfr[ni] = *(const bf16x8*)(&b_lds[cb][bOff + ni * 16 * BK]);

    #pragma unroll
    for (int mi = 0; mi < 4; ++mi)
      #pragma unroll
      for (int ni = 0; ni < 4; ++ni)
        acc[mi][ni] = __builtin_amdgcn_mfma_f32_16x16x32_bf16(
            af[mi], bfr[ni], acc[mi][ni], 0, 0, 0);
  }

  // epilogue: scale+bias in f32.  C/D: col=lane&15, row=(lane>>4)*4+reg
  const int colb = n0 + wc + r15;
  const int rowb = m0 + wr + kgrp * 4;
  #pragma unroll
  for (int ni = 0; ni < 4; ++ni) {
    const int col = colb + ni * 16;
    const float sc = S[col];
    const float bb = Bias[col];
    #pragma unroll
    for (int mi = 0; mi < 4; ++mi) {
      const int row = rowb + mi * 16;
      f32x4 a = acc[mi][ni];
      #pragma unroll
      for (int j = 0; j < 4; ++j)
        O[(size_t)(row + j) * N_TOT + col] = a[j] * sc + bb;
    }
  }
}

// ---------------- fallback: fused kernel (ws too small) ----------------
#define BSTRIDE 40
__global__ void __launch_bounds__(256)
w8a16_gemm_fused(const float* __restrict__ A, const int* __restrict__ Q,
                 const float* __restrict__ S, const float* __restrict__ Bias,
                 float* __restrict__ O)
{
  __shared__ __bf16 a_lds[BM * BK];
  __shared__ __bf16 b_lds[BN * BSTRIDE];
  const int tid = threadIdx.x, lane = tid & 63, wv = tid >> 6;
  const int bid = blockIdx.x;
  const int swz = (bid & 7) * 1024 + (bid >> 3);
  const int bx = swz >> 6, by = swz & 63;
  const int m0 = by * BM, n0 = bx * BN;
  const int mA0 = tid >> 2, mA1 = (256 + tid) >> 2;
  const int kcA = tid & 3;
  const int kp0 = kcA ^ swz_s(mA0), kp1 = kcA ^ swz_s(mA1);
  const float* pA0 = A + (size_t)(m0 + mA0) * K_TOT + kcA * 8;
  const float* pA1 = A + (size_t)(m0 + mA1) * K_TOT + kcA * 8;
  __bf16* dA0 = a_lds + mA0 * BK + kp0 * 8;
  __bf16* dA1 = a_lds + mA1 * BK + kp1 * 8;
  const int nB = tid & 127, kg = (tid >> 7) * 16;
  const int* pQ = Q + (size_t)kg * N_TOT + n0 + nB;
  __bf16* dB = b_lds + nB * BSTRIDE + kg;
  const int wr = (wv >> 1) * 64, wc = (wv & 1) * 64;
  const int r15 = lane & 15, kgrp = lane >> 4;
  const int selA = kgrp ^ swz_s(r15);
  const __bf16* aRd = a_lds + (wr + r15) * BK + selA * 8;
  const __bf16* bRd = b_lds + (wc + r15) * BSTRIDE + kgrp * 8;
  f32x4 acc[4][4];
  #pragma unroll
  for (int i = 0; i < 4; ++i)
    #pragma unroll
    for (int j = 0; j < 4; ++j) acc[i][j] = {0.f, 0.f, 0.f, 0.f};
  for (int kt = 0; kt < NT; ++kt) {
    f32x4 a0lo = *(const f32x4*)(pA0), a0hi = *(const f32x4*)(pA0 + 4);
    f32x4 a1lo = *(const f32x4*)(pA1), a1hi = *(const f32x4*)(pA1 + 4);
    pA0 += BK; pA1 += BK;
    bf16x8 a0, a1;
    #pragma unroll
    for (int i = 0; i < 4; ++i) {
      a0[i] = (__bf16)a0lo[i]; a0[i + 4] = (__bf16)a0hi[i];
      a1[i] = (__bf16)a1lo[i]; a1[i + 4] = (__bf16)a1hi[i];
    }
    int qv[16];
    #pragma unroll
    for (int i = 0; i < 16; ++i) qv[i] = pQ[(size_t)i * N_TOT];
    pQ += (size_t)BK * N_TOT;
    bf16x8 v0, v1;
    #pragma unroll
    for (int i = 0; i < 8; ++i) { v0[i] = (__bf16)(float)qv[i]; v1[i] = (__bf16)(float)qv[i + 8]; }
    *(bf16x8*)dA0 = a0; *(bf16x8*)dA1 = a1;
    *(bf16x8*)(dB) = v0; *(bf16x8*)(dB + 8) = v1;
    __syncthreads();
    bf16x8 af[4], bfr[4];
    #pragma unroll
    for (int mi = 0; mi < 4; ++mi) af[mi] = *(const bf16x8*)(aRd + mi * 16 * BK);
    #pragma unroll
    for (int ni = 0; ni < 4; ++ni) bfr[ni] = *(const bf16x8*)(bRd + ni * 16 * BSTRIDE);
    #pragma unroll
    for (int mi = 0; mi < 4; ++mi)
      #pragma unroll
      for (int ni = 0; ni < 4; ++ni)
        acc[mi][ni] = __builtin_amdgcn_mfma_f32_16x16x32_bf16(af[mi], bfr[ni], acc[mi][ni], 0, 0, 0);
    __syncthreads();
  }
  const int colb = n0 + wc + r15, rowb = m0 + wr + kgrp * 4;
  #pragma unroll
  for (int ni = 0; ni < 4; ++ni) {
    const int col = colb + ni * 16;
    const float sc = S[col], bb = Bias[col];
    #pragma unroll
    for (int mi = 0; mi < 4; ++mi) {
      const int row = rowb + mi * 16;
      f32x4 a = acc[mi][ni];
      #pragma unroll
      for (int j = 0; j < 4; ++j)
        O[(size_t)(row + j) * N_TOT + col] = a[j] * sc + bb;
    }
  }
}

extern "C" void kernel_launch(void* const* d_in, const int* in_sizes, int n_in,
                              void* d_out, int out_size, void* d_ws, size_t ws_size,
                              hipStream_t stream) {
  const float* A    = (const float*)d_in[0];
  const int*   Q    = (const int*)d_in[1];
  const float* S    = (const float*)d_in[2];
  const float* Bias = (const float*)d_in[3];
  float*       O    = (float*)d_out;

  const size_t A_BYTES = (size_t)M_TOT * K_TOT * 2;   // 64 MiB
  const size_t B_BYTES = (size_t)N_TOT * K_TOT * 2;   // 128 MiB

  if (ws_size >= A_BYTES + B_BYTES) {
    __bf16* Abf = (__bf16*)d_ws;
    __bf16* Bt  = (__bf16*)((char*)d_ws + A_BYTES);
    cvt_a_kernel<<<dim3(16384), dim3(256), 0, stream>>>(A, Abf);
    transpose_q_kernel<<<dim3(16384), dim3(256), 0, stream>>>(Q, Bt);
    w8a16_gemm_ws<<<dim3(8192), dim3(256), 0, stream>>>(Abf, Bt, S, Bias, O);
  } else {
    w8a16_gemm_fused<<<dim3(8192), dim3(256), 0, stream>>>(A, Q, S, Bias, O);
  }
}

// Round 6
// 1388.680 us; speedup vs baseline: 2.4088x; 1.1233x over previous
//
#include <hip/hip_runtime.h>
#include <stdint.h>

// W8A16 GEMM: out[m,n] = s[n] * sum_k a[m,k] * q_int8[k,n] + bias[n]
// M=8192, N=16384, K=4096. Harness dtypes: A,S,Bias f32; Q int32; OUT f32.
//
// Round 6: 256x256 tile, BK=64, 8 waves (2Mx4N, wave-tile 128x64), 2-slot
// LDS ring (128 KB dynamic), 8-chunk XOR swizzle (2-way = free), stage-first
// + single vmcnt(0)+barrier per K-tile (drain-late), setprio around MFMA.

typedef __bf16 bf16x8 __attribute__((ext_vector_type(8)));
typedef float  f32x4  __attribute__((ext_vector_type(4)));

#define M_TOT 8192
#define N_TOT 16384
#define K_TOT 4096
#define BM 256
#define BN 256
#define BK 64
#define NT (K_TOT / BK)        // 64 K-tiles
#define SLOT_ELEMS 16384       // 256 rows * 64 cols bf16 = 32 KB

__device__ __forceinline__ void gload_lds16(const void* g, void* l) {
  __builtin_amdgcn_global_load_lds(
      (const __attribute__((address_space(1))) unsigned int*)g,
      (__attribute__((address_space(3))) unsigned int*)l,
      16, 0, 0);
}

// ---------------- pre-pass 1: A f32 -> bf16 ----------------
__global__ void __launch_bounds__(256)
cvt_a_kernel(const float* __restrict__ A, __bf16* __restrict__ Abf) {
  const size_t i = ((size_t)blockIdx.x * 256 + threadIdx.x) * 8;
  f32x4 lo = *(const f32x4*)(A + i);
  f32x4 hi = *(const f32x4*)(A + i + 4);
  bf16x8 v;
  #pragma unroll
  for (int j = 0; j < 4; ++j) {
    v[j]     = (__bf16)lo[j];
    v[j + 4] = (__bf16)hi[j];
  }
  *(bf16x8*)(Abf + i) = v;
}

// ---------------- pre-pass 2: Q [K][N] int32 -> Bt [N][K] bf16 ------------
__global__ void __launch_bounds__(256)
transpose_q_kernel(const int* __restrict__ Q, __bf16* __restrict__ Bt) {
  const int bk = blockIdx.x & 63;        // 64 k-tiles
  const int bn = blockIdx.x >> 6;        // 256 n-tiles
  const int k0 = bk * 64, n0 = bn * 64;
  const int tx = threadIdx.x & 63;       // n within tile
  const int ty = threadIdx.x >> 6;       // k-chunk of 16
  const int kb = k0 + ty * 16;
  const int n  = n0 + tx;
  int q[16];
  #pragma unroll
  for (int i = 0; i < 16; ++i)
    q[i] = Q[(size_t)(kb + i) * N_TOT + n];
  bf16x8 v0, v1;
  #pragma unroll
  for (int i = 0; i < 8; ++i) {
    v0[i] = (__bf16)(float)q[i];
    v1[i] = (__bf16)(float)q[i + 8];
  }
  *(bf16x8*)(Bt + (size_t)n * K_TOT + kb)     = v0;
  *(bf16x8*)(Bt + (size_t)n * K_TOT + kb + 8) = v1;
}

// ---------------- main GEMM: 256^2 / BK=64 / 8 waves / 2-slot ring --------
__global__ void __launch_bounds__(512, 2)
w8a16_gemm_ws(const __bf16* __restrict__ A,   // [M,K] bf16
              const __bf16* __restrict__ Bt,  // [N,K] bf16
              const float*  __restrict__ S,
              const float*  __restrict__ Bias,
              float*        __restrict__ O)
{
  extern __shared__ __bf16 lds[];
  // layout: A slots [2][SLOT_ELEMS] at lds+0 ; B slots [2][SLOT_ELEMS] at lds+2*SLOT_ELEMS
  __bf16* const aBase0 = lds;
  __bf16* const bBase0 = lds + 2 * SLOT_ELEMS;

  const int tid  = threadIdx.x;
  const int lane = tid & 63;
  const int wv   = tid >> 6;     // 0..7
  const int wm   = wv >> 2;      // 0..1 : M-wave (rows wm*128)
  const int wn   = wv & 3;       // 0..3 : N-wave (cols wn*64)

  // XCD map: xcd owns 8 bx-columns; by fastest (B-panel 2MB L2-resident).
  const int bid = blockIdx.x;
  const int xcd = bid & 7;
  const int c   = bid >> 3;                 // [0,256)
  const int bx  = xcd * 8 + (c >> 5);       // [0,64)
  const int by  = c & 31;                   // [0,32)
  const int m0  = by * BM;
  const int n0  = bx * BN;

  // ---- staging geometry ----
  // chunk id x_j = j*512 + tid, j=0..3 A-slot chunks (2048), j=0..3 B.
  // row r_j = j*64 + (tid>>3); phys p = tid&7; logical c = p ^ (r&7).
  // r&7 == (tid>>3)&7 for all j (j*64 % 8 == 0) -> one swizzled col per thread.
  const int rr   = tid >> 3;                       // 0..63
  const int cswz = (tid & 7) ^ (rr & 7);           // logical chunk to fetch
  const __bf16* pa0 = A  + (size_t)(m0 + 0   + rr) * K_TOT + cswz * 8;
  const __bf16* pa1 = A  + (size_t)(m0 + 64  + rr) * K_TOT + cswz * 8;
  const __bf16* pa2 = A  + (size_t)(m0 + 128 + rr) * K_TOT + cswz * 8;
  const __bf16* pa3 = A  + (size_t)(m0 + 192 + rr) * K_TOT + cswz * 8;
  const __bf16* pb0 = Bt + (size_t)(n0 + 0   + rr) * K_TOT + cswz * 8;
  const __bf16* pb1 = Bt + (size_t)(n0 + 64  + rr) * K_TOT + cswz * 8;
  const __bf16* pb2 = Bt + (size_t)(n0 + 128 + rr) * K_TOT + cswz * 8;
  const __bf16* pb3 = Bt + (size_t)(n0 + 192 + rr) * K_TOT + cswz * 8;
  const int dA = tid * 8;                          // elems; + j*4096 per j

#define STAGE(s) do {                                                   \
    __bf16* as_ = aBase0 + (s) * SLOT_ELEMS;                            \
    __bf16* bs_ = bBase0 + (s) * SLOT_ELEMS;                            \
    gload_lds16(pa0, as_ + dA);                                         \
    gload_lds16(pa1, as_ + 4096  + dA);                                 \
    gload_lds16(pa2, as_ + 8192  + dA);                                 \
    gload_lds16(pa3, as_ + 12288 + dA);                                 \
    gload_lds16(pb0, bs_ + dA);                                         \
    gload_lds16(pb1, bs_ + 4096  + dA);                                 \
    gload_lds16(pb2, bs_ + 8192  + dA);                                 \
    gload_lds16(pb3, bs_ + 12288 + dA);                                 \
    pa0 += BK; pa1 += BK; pa2 += BK; pa3 += BK;                         \
    pb0 += BK; pb1 += BK; pb2 += BK; pb3 += BK;                         \
  } while (0)

  // ---- fragment-read constants ----
  // A frag (mi, ks): row = wm*128 + mi*16 + l15; chunk = (ks*4+quad) ^ (row&7)
  // row&7 == l15&7 (mi*16 % 8 == 0). elem addr = row*64 + phys*8.
  const int l15    = lane & 15;
  const int quad   = lane >> 4;
  const int physA0 = quad ^ (l15 & 7);
  const int aRowOff = (wm * 128 + l15) * 64;   // + mi*1024
  const int bRowOff = (wn * 64  + l15) * 64;   // + ni*1024

  f32x4 acc[8][4];
  #pragma unroll
  for (int i = 0; i < 8; ++i)
    #pragma unroll
    for (int j = 0; j < 4; ++j)
      acc[i][j] = {0.f, 0.f, 0.f, 0.f};

  // prologue: stage tile 0 -> slot 0 (cold drain, once)
  STAGE(0);
  asm volatile("s_waitcnt vmcnt(0)" ::: "memory");
  __builtin_amdgcn_s_barrier();
  __builtin_amdgcn_sched_barrier(0);

  for (int kt = 0; kt < NT; ++kt) {
    const int ct = kt & 1;

    // stage next tile FIRST (max issue-to-demand cover ~ one full tile)
    if (kt + 1 < NT) STAGE(ct ^ 1);

    const __bf16* aB = aBase0 + ct * SLOT_ELEMS + aRowOff;
    const __bf16* bB = bBase0 + ct * SLOT_ELEMS + bRowOff;

    #pragma unroll
    for (int ks = 0; ks < 2; ++ks) {
      const int ph = physA0 ^ (ks << 2);
      bf16x8 af[8], bfr[4];
      #pragma unroll
      for (int mi = 0; mi < 8; ++mi)
        af[mi] = *(const bf16x8*)(aB + mi * 1024 + ph * 8);
      #pragma unroll
      for (int ni = 0; ni < 4; ++ni)
        bfr[ni] = *(const bf16x8*)(bB + ni * 1024 + ph * 8);

      __builtin_amdgcn_s_setprio(1);
      #pragma unroll
      for (int mi = 0; mi < 8; ++mi)
        #pragma unroll
        for (int ni = 0; ni < 4; ++ni)
          acc[mi][ni] = __builtin_amdgcn_mfma_f32_16x16x32_bf16(
              af[mi], bfr[ni], acc[mi][ni], 0, 0, 0);
      __builtin_amdgcn_s_setprio(0);
    }

    if (kt + 1 < NT) {
      // tile kt+1 fully landed (cover = this tile's reads+64 MFMA), flip.
      asm volatile("s_waitcnt vmcnt(0)" ::: "memory");
      __builtin_amdgcn_s_barrier();
      __builtin_amdgcn_sched_barrier(0);
    }
  }
#undef STAGE

  // ---- epilogue: scale+bias, f32 stores ----
  // C/D per 16x16: col = lane&15, row = (lane>>4)*4 + reg  [m89-verified]
  const int colb = n0 + wn * 64 + l15;
  const int rowb = m0 + wm * 128 + quad * 4;
  #pragma unroll
  for (int ni = 0; ni < 4; ++ni) {
    const int col = colb + ni * 16;
    const float sc = S[col];
    const float bb = Bias[col];
    #pragma unroll
    for (int mi = 0; mi < 8; ++mi) {
      const int row = rowb + mi * 16;
      f32x4 a = acc[mi][ni];
      #pragma unroll
      for (int j = 0; j < 4; ++j)
        O[(size_t)(row + j) * N_TOT + col] = a[j] * sc + bb;
    }
  }
}

// ---------------- fallback: fused kernel (ws too small) ----------------
#define FBM 128
#define FBN 128
#define FBK 32
#define BSTRIDE 40
__device__ __forceinline__ int swz_s(int row) {
  return (row & 3) ^ ((row >> 2) & 1);
}
__global__ void __launch_bounds__(256)
w8a16_gemm_fused(const float* __restrict__ A, const int* __restrict__ Q,
                 const float* __restrict__ S, const float* __restrict__ Bias,
                 float* __restrict__ O)
{
  __shared__ __bf16 a_lds[FBM * FBK];
  __shared__ __bf16 b_lds[FBN * BSTRIDE];
  const int tid = threadIdx.x, lane = tid & 63, wv = tid >> 6;
  const int bid = blockIdx.x;
  const int swz = (bid & 7) * 1024 + (bid >> 3);
  const int bx = swz >> 6, by = swz & 63;
  const int m0 = by * FBM, n0 = bx * FBN;
  const int mA0 = tid >> 2, mA1 = (256 + tid) >> 2;
  const int kcA = tid & 3;
  const int kp0 = kcA ^ swz_s(mA0), kp1 = kcA ^ swz_s(mA1);
  const float* pA0 = A + (size_t)(m0 + mA0) * K_TOT + kcA * 8;
  const float* pA1 = A + (size_t)(m0 + mA1) * K_TOT + kcA * 8;
  __bf16* dA0 = a_lds + mA0 * FBK + kp0 * 8;
  __bf16* dA1 = a_lds + mA1 * FBK + kp1 * 8;
  const int nB = tid & 127, kg = (tid >> 7) * 16;
  const int* pQ = Q + (size_t)kg * N_TOT + n0 + nB;
  __bf16* dB = b_lds + nB * BSTRIDE + kg;
  const int wr = (wv >> 1) * 64, wc = (wv & 1) * 64;
  const int r15 = lane & 15, kgrp = lane >> 4;
  const int selA = kgrp ^ swz_s(r15);
  const __bf16* aRd = a_lds + (wr + r15) * FBK + selA * 8;
  const __bf16* bRd = b_lds + (wc + r15) * BSTRIDE + kgrp * 8;
  f32x4 acc[4][4];
  #pragma unroll
  for (int i = 0; i < 4; ++i)
    #pragma unroll
    for (int j = 0; j < 4; ++j) acc[i][j] = {0.f, 0.f, 0.f, 0.f};
  for (int kt = 0; kt < K_TOT / FBK; ++kt) {
    f32x4 a0lo = *(const f32x4*)(pA0), a0hi = *(const f32x4*)(pA0 + 4);
    f32x4 a1lo = *(const f32x4*)(pA1), a1hi = *(const f32x4*)(pA1 + 4);
    pA0 += FBK; pA1 += FBK;
    bf16x8 a0, a1;
    #pragma unroll
    for (int i = 0; i < 4; ++i) {
      a0[i] = (__bf16)a0lo[i]; a0[i + 4] = (__bf16)a0hi[i];
      a1[i] = (__bf16)a1lo[i]; a1[i + 4] = (__bf16)a1hi[i];
    }
    int qv[16];
    #pragma unroll
    for (int i = 0; i < 16; ++i) qv[i] = pQ[(size_t)i * N_TOT];
    pQ += (size_t)FBK * N_TOT;
    bf16x8 v0, v1;
    #pragma unroll
    for (int i = 0; i < 8; ++i) { v0[i] = (__bf16)(float)qv[i]; v1[i] = (__bf16)(float)qv[i + 8]; }
    *(bf16x8*)dA0 = a0; *(bf16x8*)dA1 = a1;
    *(bf16x8*)(dB) = v0; *(bf16x8*)(dB + 8) = v1;
    __syncthreads();
    bf16x8 af[4], bfr[4];
    #pragma unroll
    for (int mi = 0; mi < 4; ++mi) af[mi] = *(const bf16x8*)(aRd + mi * 16 * FBK);
    #pragma unroll
    for (int ni = 0; ni < 4; ++ni) bfr[ni] = *(const bf16x8*)(bRd + ni * 16 * BSTRIDE);
    #pragma unroll
    for (int mi = 0; mi < 4; ++mi)
      #pragma unroll
      for (int ni = 0; ni < 4; ++ni)
        acc[mi][ni] = __builtin_amdgcn_mfma_f32_16x16x32_bf16(af[mi], bfr[ni], acc[mi][ni], 0, 0, 0);
    __syncthreads();
  }
  const int colb = n0 + wc + r15, rowb = m0 + wr + kgrp * 4;
  #pragma unroll
  for (int ni = 0; ni < 4; ++ni) {
    const int col = colb + ni * 16;
    const float sc = S[col], bb = Bias[col];
    #pragma unroll
    for (int mi = 0; mi < 4; ++mi) {
      const int row = rowb + mi * 16;
      f32x4 a = acc[mi][ni];
      #pragma unroll
      for (int j = 0; j < 4; ++j)
        O[(size_t)(row + j) * N_TOT + col] = a[j] * sc + bb;
    }
  }
}

extern "C" void kernel_launch(void* const* d_in, const int* in_sizes, int n_in,
                              void* d_out, int out_size, void* d_ws, size_t ws_size,
                              hipStream_t stream) {
  const float* A    = (const float*)d_in[0];
  const int*   Q    = (const int*)d_in[1];
  const float* S    = (const float*)d_in[2];
  const float* Bias = (const float*)d_in[3];
  float*       O    = (float*)d_out;

  const size_t A_BYTES = (size_t)M_TOT * K_TOT * 2;   // 64 MiB
  const size_t B_BYTES = (size_t)N_TOT * K_TOT * 2;   // 128 MiB

  if (ws_size >= A_BYTES + B_BYTES) {
    __bf16* Abf = (__bf16*)d_ws;
    __bf16* Bt  = (__bf16*)((char*)d_ws + A_BYTES);
    cvt_a_kernel<<<dim3(16384), dim3(256), 0, stream>>>(A, Abf);
    transpose_q_kernel<<<dim3(16384), dim3(256), 0, stream>>>(Q, Bt);
    // grid = (M/256)*(N/256) = 32*64 = 2048 blocks, 512 threads, 128 KB LDS
    w8a16_gemm_ws<<<dim3(2048), dim3(512), 131072, stream>>>(Abf, Bt, S, Bias, O);
  } else {
    w8a16_gemm_fused<<<dim3(8192), dim3(256), 0, stream>>>(A, Q, S, Bias, O);
  }
}